// Round 6
// baseline (221.746 us; speedup 1.0000x reference)
//
#include <hip/hip_runtime.h>
#include <hip/hip_bf16.h>

#define MODEL_DIM 256
#define HIST 8
#define HID 512
#define NNEUR 64
#define IN_DIM 2304   // MODEL_DIM * (1 + HIST)
#define BATCH 32

__device__ __forceinline__ float geluf(float x) {
    return 0.5f * x * (1.0f + erff(x * 0.70710678118654752440f));
}

// ---------------------------------------------------------------------------
// K0: x[b][0:256] = emb[b] @ Wp + bp ; x[b][256:2304] = pre_activations flat
// ---------------------------------------------------------------------------
__global__ __launch_bounds__(256) void k_build_x(
        const float* __restrict__ emb, const float* __restrict__ pre,
        const float* __restrict__ Wp, const float* __restrict__ bp,
        float* __restrict__ x) {
    const int b = blockIdx.x;
    const int d = threadIdx.x;

    __shared__ float e[MODEL_DIM];
    e[d] = emb[b * MODEL_DIM + d];
    __syncthreads();

    float acc = bp[d];
    #pragma unroll 4
    for (int k = 0; k < MODEL_DIM; ++k)
        acc = fmaf(e[k], Wp[(size_t)k * MODEL_DIM + d], acc);
    x[b * IN_DIM + d] = acc;

    #pragma unroll
    for (int r = 0; r < HIST; ++r)
        x[b * IN_DIM + MODEL_DIM + r * MODEL_DIM + d] = pre[r * MODEL_DIM + d];
}

// ---------------------------------------------------------------------------
// K1: layer1. grid 512 = n(64) x ks(8: K=288). block 512 = 8 waves.
// thread: cg = t&127 -> 4 cols, rg = t>>7 -> 8 rows.
// 2-deep software pipeline, batch 6: ~6 dwordx4 in flight per wave.
// p1[8][64][32][512] f32
// ---------------------------------------------------------------------------
__global__ __launch_bounds__(512, 4) void k_layer1(
        const float* __restrict__ x, const float* __restrict__ W1,
        float* __restrict__ p1) {
    const int n  = blockIdx.x >> 3;
    const int ks = blockIdx.x & 7;
    const int t  = threadIdx.x;
    const int cg = t & 127;
    const int rg = t >> 7;
    const int col0 = cg * 4;
    const int row0 = rg * 8;
    const int k0 = ks * 288;

    __shared__ float xs[BATCH][288];
    #pragma unroll
    for (int q = 0; q < 5; ++q) {                 // 32*72 float4 = 2304
        int fi = t + 512 * q;
        if (fi < 2304) {
            int row = fi / 72;
            int c4  = fi - row * 72;
            *((float4*)&xs[row][c4 * 4]) =
                *((const float4*)(x + (size_t)row * IN_DIM + k0 + c4 * 4));
        }
    }
    __syncthreads();

    const float* W = W1 + (size_t)n * IN_DIM * HID + (size_t)k0 * HID + col0;

    float acc[8][4];
    #pragma unroll
    for (int i = 0; i < 8; ++i)
        #pragma unroll
        for (int j = 0; j < 4; ++j) acc[i][j] = 0.0f;

    float4 w0[6], w1[6];
    #pragma unroll
    for (int j = 0; j < 6; ++j)
        w0[j] = *((const float4*)(W + (size_t)j * HID));

    for (int kk = 0; kk < 288; kk += 12) {
        #pragma unroll
        for (int j = 0; j < 6; ++j)
            w1[j] = *((const float4*)(W + (size_t)(kk + 6 + j) * HID));
        #pragma unroll
        for (int j = 0; j < 6; ++j) {
            #pragma unroll
            for (int i = 0; i < 8; ++i) {
                float xv = xs[row0 + i][kk + j];
                acc[i][0] = fmaf(xv, w0[j].x, acc[i][0]);
                acc[i][1] = fmaf(xv, w0[j].y, acc[i][1]);
                acc[i][2] = fmaf(xv, w0[j].z, acc[i][2]);
                acc[i][3] = fmaf(xv, w0[j].w, acc[i][3]);
            }
        }
        const int nb = (kk + 12 <= 276) ? kk + 12 : 276;   // clamp: dead last prefetch stays in-bounds
        #pragma unroll
        for (int j = 0; j < 6; ++j)
            w0[j] = *((const float4*)(W + (size_t)(nb + j) * HID));
        #pragma unroll
        for (int j = 0; j < 6; ++j) {
            #pragma unroll
            for (int i = 0; i < 8; ++i) {
                float xv = xs[row0 + i][kk + 6 + j];
                acc[i][0] = fmaf(xv, w1[j].x, acc[i][0]);
                acc[i][1] = fmaf(xv, w1[j].y, acc[i][1]);
                acc[i][2] = fmaf(xv, w1[j].z, acc[i][2]);
                acc[i][3] = fmaf(xv, w1[j].w, acc[i][3]);
            }
        }
    }
    float* P = p1 + (size_t)(ks * NNEUR + n) * BATCH * HID;
    #pragma unroll
    for (int i = 0; i < 8; ++i)
        *((float4*)(P + (size_t)(row0 + i) * HID + col0)) =
            make_float4(acc[i][0], acc[i][1], acc[i][2], acc[i][3]);
}

// ---------------------------------------------------------------------------
// K2: layer2. h1 = gelu(sum p1[0..7] + b1) staged once per block.
// grid 512 = n(64) x ch(2: 256 cols) x ks(4: K=128). block 512.
// thread: cg = t&63 -> 4 cols, rg = t>>6 -> 4 rows.
// 2-deep pipeline, batch 8. p2[4][64][32][512] f32
// ---------------------------------------------------------------------------
__global__ __launch_bounds__(512, 4) void k_layer2(
        const float* __restrict__ p1, const float* __restrict__ b1,
        const float* __restrict__ W2, float* __restrict__ p2) {
    const int bid = blockIdx.x;
    const int n  = bid >> 3;
    const int ch = (bid >> 2) & 1;
    const int ks = bid & 3;
    const int t  = threadIdx.x;
    const int cg = t & 63;
    const int rg = t >> 6;
    const int col0 = ch * 256 + cg * 4;
    const int row0 = rg * 4;
    const int k0 = ks * 128;

    const size_t sl = (size_t)NNEUR * BATCH * HID;

    __shared__ float xs[BATCH][128];
    #pragma unroll
    for (int q = 0; q < 2; ++q) {                 // 32*32 float4 = 1024
        int fi  = t + 512 * q;
        int row = fi >> 5;
        int c4  = fi & 31;
        const float* a = p1 + ((size_t)n * BATCH + row) * HID + k0 + c4 * 4;
        float4 s0 = *((const float4*)(a));
        float4 s1 = *((const float4*)(a + sl));
        float4 s2 = *((const float4*)(a + 2 * sl));
        float4 s3 = *((const float4*)(a + 3 * sl));
        float4 s4 = *((const float4*)(a + 4 * sl));
        float4 s5 = *((const float4*)(a + 5 * sl));
        float4 s6 = *((const float4*)(a + 6 * sl));
        float4 s7 = *((const float4*)(a + 7 * sl));
        float4 bb = *((const float4*)(b1 + (size_t)n * HID + k0 + c4 * 4));
        *((float4*)&xs[row][c4 * 4]) = make_float4(
            geluf(s0.x+s1.x+s2.x+s3.x+s4.x+s5.x+s6.x+s7.x + bb.x),
            geluf(s0.y+s1.y+s2.y+s3.y+s4.y+s5.y+s6.y+s7.y + bb.y),
            geluf(s0.z+s1.z+s2.z+s3.z+s4.z+s5.z+s6.z+s7.z + bb.z),
            geluf(s0.w+s1.w+s2.w+s3.w+s4.w+s5.w+s6.w+s7.w + bb.w));
    }
    __syncthreads();

    const float* W = W2 + (size_t)n * HID * HID + (size_t)k0 * HID + col0;

    float acc[4][4];
    #pragma unroll
    for (int i = 0; i < 4; ++i)
        #pragma unroll
        for (int j = 0; j < 4; ++j) acc[i][j] = 0.0f;

    float4 w0[8], w1[8];
    #pragma unroll
    for (int j = 0; j < 8; ++j)
        w0[j] = *((const float4*)(W + (size_t)j * HID));

    for (int kk = 0; kk < 128; kk += 16) {
        #pragma unroll
        for (int j = 0; j < 8; ++j)
            w1[j] = *((const float4*)(W + (size_t)(kk + 8 + j) * HID));
        #pragma unroll
        for (int j = 0; j < 8; ++j) {
            #pragma unroll
            for (int i = 0; i < 4; ++i) {
                float xv = xs[row0 + i][kk + j];
                acc[i][0] = fmaf(xv, w0[j].x, acc[i][0]);
                acc[i][1] = fmaf(xv, w0[j].y, acc[i][1]);
                acc[i][2] = fmaf(xv, w0[j].z, acc[i][2]);
                acc[i][3] = fmaf(xv, w0[j].w, acc[i][3]);
            }
        }
        const int nb = (kk + 16 <= 112) ? kk + 16 : 112;
        #pragma unroll
        for (int j = 0; j < 8; ++j)
            w0[j] = *((const float4*)(W + (size_t)(nb + j) * HID));
        #pragma unroll
        for (int j = 0; j < 8; ++j) {
            #pragma unroll
            for (int i = 0; i < 4; ++i) {
                float xv = xs[row0 + i][kk + 8 + j];
                acc[i][0] = fmaf(xv, w1[j].x, acc[i][0]);
                acc[i][1] = fmaf(xv, w1[j].y, acc[i][1]);
                acc[i][2] = fmaf(xv, w1[j].z, acc[i][2]);
                acc[i][3] = fmaf(xv, w1[j].w, acc[i][3]);
            }
        }
    }
    float* P = p2 + (size_t)(ks * NNEUR + n) * BATCH * HID;
    #pragma unroll
    for (int i = 0; i < 4; ++i)
        *((float4*)(P + (size_t)(row0 + i) * HID + col0)) =
            make_float4(acc[i][0], acc[i][1], acc[i][2], acc[i][3]);
}

// ---------------------------------------------------------------------------
// K3: layer3. h2 = gelu(sum p2[0..3] + b2). grid 512 = n(64) x ks(8: K=64).
// block 512: cg = t&63 -> 4 cols (256), rg = t>>6 -> 4 rows.
// 2-deep pipeline, batch 8. p3[8][64][32][256] f32 (aliases p1)
// ---------------------------------------------------------------------------
__global__ __launch_bounds__(512, 4) void k_layer3(
        const float* __restrict__ p2, const float* __restrict__ b2,
        const float* __restrict__ W3, float* __restrict__ p3) {
    const int n  = blockIdx.x >> 3;
    const int ks = blockIdx.x & 7;
    const int t  = threadIdx.x;
    const int cg = t & 63;
    const int rg = t >> 6;
    const int col0 = cg * 4;
    const int row0 = rg * 4;
    const int k0 = ks * 64;

    const size_t sl = (size_t)NNEUR * BATCH * HID;

    __shared__ float xs[BATCH][64];
    {                                             // 32*16 float4 = 512
        int row = t >> 4;
        int c4  = t & 15;
        const float* a = p2 + ((size_t)n * BATCH + row) * HID + k0 + c4 * 4;
        float4 s0 = *((const float4*)(a));
        float4 s1 = *((const float4*)(a + sl));
        float4 s2 = *((const float4*)(a + 2 * sl));
        float4 s3 = *((const float4*)(a + 3 * sl));
        float4 bb = *((const float4*)(b2 + (size_t)n * HID + k0 + c4 * 4));
        *((float4*)&xs[row][c4 * 4]) = make_float4(
            geluf(s0.x+s1.x+s2.x+s3.x + bb.x),
            geluf(s0.y+s1.y+s2.y+s3.y + bb.y),
            geluf(s0.z+s1.z+s2.z+s3.z + bb.z),
            geluf(s0.w+s1.w+s2.w+s3.w + bb.w));
    }
    __syncthreads();

    const float* W = W3 + (size_t)n * HID * MODEL_DIM + (size_t)k0 * MODEL_DIM + col0;

    float acc[4][4];
    #pragma unroll
    for (int i = 0; i < 4; ++i)
        #pragma unroll
        for (int j = 0; j < 4; ++j) acc[i][j] = 0.0f;

    float4 w0[8], w1[8];
    #pragma unroll
    for (int j = 0; j < 8; ++j)
        w0[j] = *((const float4*)(W + (size_t)j * MODEL_DIM));

    for (int kk = 0; kk < 64; kk += 16) {
        #pragma unroll
        for (int j = 0; j < 8; ++j)
            w1[j] = *((const float4*)(W + (size_t)(kk + 8 + j) * MODEL_DIM));
        #pragma unroll
        for (int j = 0; j < 8; ++j) {
            #pragma unroll
            for (int i = 0; i < 4; ++i) {
                float xv = xs[row0 + i][kk + j];
                acc[i][0] = fmaf(xv, w0[j].x, acc[i][0]);
                acc[i][1] = fmaf(xv, w0[j].y, acc[i][1]);
                acc[i][2] = fmaf(xv, w0[j].z, acc[i][2]);
                acc[i][3] = fmaf(xv, w0[j].w, acc[i][3]);
            }
        }
        const int nb = (kk + 16 <= 48) ? kk + 16 : 48;
        #pragma unroll
        for (int j = 0; j < 8; ++j)
            w0[j] = *((const float4*)(W + (size_t)(nb + j) * MODEL_DIM));
        #pragma unroll
        for (int j = 0; j < 8; ++j) {
            #pragma unroll
            for (int i = 0; i < 4; ++i) {
                float xv = xs[row0 + i][kk + 8 + j];
                acc[i][0] = fmaf(xv, w1[j].x, acc[i][0]);
                acc[i][1] = fmaf(xv, w1[j].y, acc[i][1]);
                acc[i][2] = fmaf(xv, w1[j].z, acc[i][2]);
                acc[i][3] = fmaf(xv, w1[j].w, acc[i][3]);
            }
        }
    }
    float* P = p3 + (size_t)(ks * NNEUR + n) * BATCH * MODEL_DIM;
    #pragma unroll
    for (int i = 0; i < 4; ++i)
        *((float4*)(P + (size_t)(row0 + i) * MODEL_DIM + col0)) =
            make_float4(acc[i][0], acc[i][1], acc[i][2], acc[i][3]);
}

// ---------------------------------------------------------------------------
// K4: y = sum(p3[0..7]) + b3 ; LayerNorm ; oscillator mod ; f32 store
// ---------------------------------------------------------------------------
__global__ __launch_bounds__(256) void k_final(
        const float* __restrict__ p3, const float* __restrict__ b3,
        const float* __restrict__ gamma, const float* __restrict__ beta,
        const int* __restrict__ tick, float* __restrict__ out) {
    const int n  = blockIdx.x >> 3;
    const int bq = blockIdx.x & 7;
    const int t  = threadIdx.x;
    const int w  = t >> 6;
    const int lane = t & 63;
    const int b  = bq * 4 + w;

    const size_t par0 = (size_t)n * MODEL_DIM;
    const size_t rowoff = ((size_t)n * BATCH + b) * MODEL_DIM;
    const size_t sl = (size_t)NNEUR * BATCH * MODEL_DIM;

    float y[4];
    #pragma unroll
    for (int j = 0; j < 4; ++j) {
        int d = lane + 64 * j;
        float v = b3[par0 + d];
        #pragma unroll
        for (int s = 0; s < 8; ++s)
            v += p3[s * sl + rowoff + d];
        y[j] = v;
    }
    float s = y[0] + y[1] + y[2] + y[3];
    #pragma unroll
    for (int off = 32; off > 0; off >>= 1) s += __shfl_xor(s, off);
    float mu = s * (1.0f / 256.0f);
    float q = 0.0f;
    #pragma unroll
    for (int j = 0; j < 4; ++j) { float d0 = y[j] - mu; q = fmaf(d0, d0, q); }
    #pragma unroll
    for (int off = 32; off > 0; off >>= 1) q += __shfl_xor(q, off);
    float inv = rsqrtf(q * (1.0f / 256.0f) + 1e-5f);

    const double TWO_PI = 6.283185307179586476925287;
    double freq  = 0.5 * pow(80.0, (double)n * (1.0 / 63.0));
    double phase = fmod((double)n * 2.3571, TWO_PI);
    double tt    = (double)(*tick) * 0.1;
    float mod = (float)(1.0 + 0.5 * sin(TWO_PI * freq * tt + phase));

    #pragma unroll
    for (int j = 0; j < 4; ++j) {
        int d = lane + 64 * j;
        float o = (y[j] - mu) * inv * gamma[par0 + d] + beta[par0 + d];
        o *= mod;
        out[((size_t)b * NNEUR + n) * MODEL_DIM + d] = o;
    }
}

// ---------------------------------------------------------------------------
extern "C" void kernel_launch(void* const* d_in, const int* in_sizes, int n_in,
                              void* d_out, int out_size, void* d_ws, size_t ws_size,
                              hipStream_t stream) {
    const float* emb  = (const float*)d_in[0];
    const float* pre  = (const float*)d_in[1];
    const float* Wp   = (const float*)d_in[2];
    const float* bp   = (const float*)d_in[3];
    const float* W1   = (const float*)d_in[4];
    const float* b1   = (const float*)d_in[5];
    const float* W2   = (const float*)d_in[6];
    const float* b2   = (const float*)d_in[7];
    const float* W3   = (const float*)d_in[8];
    const float* b3   = (const float*)d_in[9];
    const float* gam  = (const float*)d_in[10];
    const float* bet  = (const float*)d_in[11];
    const int* tick   = (const int*)d_in[12];

    float* ws = (float*)d_ws;
    float* x  = ws;                      // 32*2304          =   73728 f32
    float* p1 = x  + 73728;              // [8][64][32][512] = 8388608 f32
    float* p2 = p1 + 8388608;            // [4][64][32][512] = 4194304 f32
    float* p3 = p1;                      // [8][64][32][256] = 4194304 f32 (aliases dead p1)
    float* out = (float*)d_out;

    k_build_x<<<32,  256, 0, stream>>>(emb, pre, Wp, bp, x);
    k_layer1 <<<512, 512, 0, stream>>>(x, W1, p1);
    k_layer2 <<<512, 512, 0, stream>>>(p1, b1, W2, p2);
    k_layer3 <<<512, 512, 0, stream>>>(p2, b2, W3, p3);
    k_final  <<<512, 256, 0, stream>>>(p3, b3, gam, bet, tick, out);
}

// Round 7
// 214.996 us; speedup vs baseline: 1.0314x; 1.0314x over previous
//
#include <hip/hip_runtime.h>
#include <hip/hip_bf16.h>

#define MODEL_DIM 256
#define HIST 8
#define HID 512
#define NNEUR 64
#define IN_DIM 2304   // MODEL_DIM * (1 + HIST)
#define BATCH 32

__device__ __forceinline__ float geluf(float x) {
    return 0.5f * x * (1.0f + erff(x * 0.70710678118654752440f));
}
__device__ __forceinline__ float f4c(const float4& v, int j) {
    switch (j) { case 0: return v.x; case 1: return v.y; case 2: return v.z; default: return v.w; }
}

// ---------------------------------------------------------------------------
// K0: x[b][0:256] = emb[b] @ Wp + bp ; x[b][256:2304] = pre_activations flat
// ---------------------------------------------------------------------------
__global__ __launch_bounds__(256) void k_build_x(
        const float* __restrict__ emb, const float* __restrict__ pre,
        const float* __restrict__ Wp, const float* __restrict__ bp,
        float* __restrict__ x) {
    const int b = blockIdx.x;
    const int d = threadIdx.x;

    __shared__ float e[MODEL_DIM];
    e[d] = emb[b * MODEL_DIM + d];
    __syncthreads();

    float acc = bp[d];
    #pragma unroll 4
    for (int k = 0; k < MODEL_DIM; ++k)
        acc = fmaf(e[k], Wp[(size_t)k * MODEL_DIM + d], acc);
    x[b * IN_DIM + d] = acc;

    #pragma unroll
    for (int r = 0; r < HIST; ++r)
        x[b * IN_DIM + MODEL_DIM + r * MODEL_DIM + d] = pre[r * MODEL_DIM + d];
}

// ---------------------------------------------------------------------------
// K1: layer1. grid 512 = n(64) x ks(8: K=288). block 256 = 4 waves.
// thread: cg = t&63 -> cols {4cg, 256+4cg} (8 cols), rg = t>>6 -> 8 rows.
// x via ds_read_b128 (4 k per read). 1 LDS op per 32 FMA.
// p1[8][64][32][512] f32
// ---------------------------------------------------------------------------
__global__ __launch_bounds__(256, 2) void k_layer1(
        const float* __restrict__ x, const float* __restrict__ W1,
        float* __restrict__ p1) {
    const int n  = blockIdx.x >> 3;
    const int ks = blockIdx.x & 7;
    const int t  = threadIdx.x;
    const int cg = t & 63;
    const int rg = t >> 6;
    const int colA = cg * 4;           // second half at colA + 256
    const int row0 = rg * 8;
    const int k0 = ks * 288;

    __shared__ float xs[BATCH][288];
    #pragma unroll
    for (int q = 0; q < 9; ++q) {                 // 32*72 float4 = 2304
        int fi  = t + 256 * q;
        int row = fi / 72;
        int c4  = fi - row * 72;
        *((float4*)&xs[row][c4 * 4]) =
            *((const float4*)(x + (size_t)row * IN_DIM + k0 + c4 * 4));
    }
    __syncthreads();

    const float* W = W1 + (size_t)n * IN_DIM * HID + (size_t)k0 * HID + colA;

    float acc[8][8];
    #pragma unroll
    for (int i = 0; i < 8; ++i)
        #pragma unroll
        for (int j = 0; j < 8; ++j) acc[i][j] = 0.0f;

    for (int kg = 0; kg < 288; kg += 4) {
        float4 xv[8];
        #pragma unroll
        for (int i = 0; i < 8; ++i)
            xv[i] = *((const float4*)&xs[row0 + i][kg]);
        #pragma unroll
        for (int j = 0; j < 4; ++j) {
            const float* Wr = W + (size_t)(kg + j) * HID;
            float4 wa = *((const float4*)(Wr));
            float4 wb = *((const float4*)(Wr + 256));
            #pragma unroll
            for (int i = 0; i < 8; ++i) {
                float xvv = f4c(xv[i], j);
                acc[i][0] = fmaf(xvv, wa.x, acc[i][0]);
                acc[i][1] = fmaf(xvv, wa.y, acc[i][1]);
                acc[i][2] = fmaf(xvv, wa.z, acc[i][2]);
                acc[i][3] = fmaf(xvv, wa.w, acc[i][3]);
                acc[i][4] = fmaf(xvv, wb.x, acc[i][4]);
                acc[i][5] = fmaf(xvv, wb.y, acc[i][5]);
                acc[i][6] = fmaf(xvv, wb.z, acc[i][6]);
                acc[i][7] = fmaf(xvv, wb.w, acc[i][7]);
            }
        }
    }
    float* P = p1 + (size_t)(ks * NNEUR + n) * BATCH * HID;
    #pragma unroll
    for (int i = 0; i < 8; ++i) {
        float* Pr = P + (size_t)(row0 + i) * HID + colA;
        *((float4*)(Pr))       = make_float4(acc[i][0], acc[i][1], acc[i][2], acc[i][3]);
        *((float4*)(Pr + 256)) = make_float4(acc[i][4], acc[i][5], acc[i][6], acc[i][7]);
    }
}

// ---------------------------------------------------------------------------
// K2: layer2. h1 = gelu(sum p1[0..7] + b1) staged. grid 512 = n(64) x ks(8:
// K=64). block 256: cg = t&63 -> cols {4cg, 256+4cg}, rg = t>>6 -> 8 rows.
// p2[8][64][32][512] f32
// ---------------------------------------------------------------------------
__global__ __launch_bounds__(256, 2) void k_layer2(
        const float* __restrict__ p1, const float* __restrict__ b1,
        const float* __restrict__ W2, float* __restrict__ p2) {
    const int n  = blockIdx.x >> 3;
    const int ks = blockIdx.x & 7;
    const int t  = threadIdx.x;
    const int cg = t & 63;
    const int rg = t >> 6;
    const int colA = cg * 4;
    const int row0 = rg * 8;
    const int k0 = ks * 64;

    const size_t sl = (size_t)NNEUR * BATCH * HID;

    __shared__ float xs[BATCH][64];
    #pragma unroll
    for (int q = 0; q < 2; ++q) {                 // 32*16 float4 = 512
        int fi  = t + 256 * q;
        int row = fi >> 4;
        int c4  = fi & 15;
        const float* a = p1 + ((size_t)n * BATCH + row) * HID + k0 + c4 * 4;
        float4 s0 = *((const float4*)(a));
        float4 s1 = *((const float4*)(a + sl));
        float4 s2 = *((const float4*)(a + 2 * sl));
        float4 s3 = *((const float4*)(a + 3 * sl));
        float4 s4 = *((const float4*)(a + 4 * sl));
        float4 s5 = *((const float4*)(a + 5 * sl));
        float4 s6 = *((const float4*)(a + 6 * sl));
        float4 s7 = *((const float4*)(a + 7 * sl));
        float4 bb = *((const float4*)(b1 + (size_t)n * HID + k0 + c4 * 4));
        *((float4*)&xs[row][c4 * 4]) = make_float4(
            geluf(s0.x+s1.x+s2.x+s3.x+s4.x+s5.x+s6.x+s7.x + bb.x),
            geluf(s0.y+s1.y+s2.y+s3.y+s4.y+s5.y+s6.y+s7.y + bb.y),
            geluf(s0.z+s1.z+s2.z+s3.z+s4.z+s5.z+s6.z+s7.z + bb.z),
            geluf(s0.w+s1.w+s2.w+s3.w+s4.w+s5.w+s6.w+s7.w + bb.w));
    }
    __syncthreads();

    const float* W = W2 + (size_t)n * HID * HID + (size_t)k0 * HID + colA;

    float acc[8][8];
    #pragma unroll
    for (int i = 0; i < 8; ++i)
        #pragma unroll
        for (int j = 0; j < 8; ++j) acc[i][j] = 0.0f;

    for (int kg = 0; kg < 64; kg += 4) {
        float4 xv[8];
        #pragma unroll
        for (int i = 0; i < 8; ++i)
            xv[i] = *((const float4*)&xs[row0 + i][kg]);
        #pragma unroll
        for (int j = 0; j < 4; ++j) {
            const float* Wr = W + (size_t)(kg + j) * HID;
            float4 wa = *((const float4*)(Wr));
            float4 wb = *((const float4*)(Wr + 256));
            #pragma unroll
            for (int i = 0; i < 8; ++i) {
                float xvv = f4c(xv[i], j);
                acc[i][0] = fmaf(xvv, wa.x, acc[i][0]);
                acc[i][1] = fmaf(xvv, wa.y, acc[i][1]);
                acc[i][2] = fmaf(xvv, wa.z, acc[i][2]);
                acc[i][3] = fmaf(xvv, wa.w, acc[i][3]);
                acc[i][4] = fmaf(xvv, wb.x, acc[i][4]);
                acc[i][5] = fmaf(xvv, wb.y, acc[i][5]);
                acc[i][6] = fmaf(xvv, wb.z, acc[i][6]);
                acc[i][7] = fmaf(xvv, wb.w, acc[i][7]);
            }
        }
    }
    float* P = p2 + (size_t)(ks * NNEUR + n) * BATCH * HID;
    #pragma unroll
    for (int i = 0; i < 8; ++i) {
        float* Pr = P + (size_t)(row0 + i) * HID + colA;
        *((float4*)(Pr))       = make_float4(acc[i][0], acc[i][1], acc[i][2], acc[i][3]);
        *((float4*)(Pr + 256)) = make_float4(acc[i][4], acc[i][5], acc[i][6], acc[i][7]);
    }
}

// ---------------------------------------------------------------------------
// K3: layer3. h2 = gelu(sum p2[0..7] + b2) staged. grid 512 = n(64) x ks(8:
// K=64). block 256: cg = t&63 -> 4 cols (256 total), rg = t>>6 -> 8 rows.
// p3[8][64][32][256] f32 (aliases p1)
// ---------------------------------------------------------------------------
__global__ __launch_bounds__(256, 2) void k_layer3(
        const float* __restrict__ p2, const float* __restrict__ b2,
        const float* __restrict__ W3, float* __restrict__ p3) {
    const int n  = blockIdx.x >> 3;
    const int ks = blockIdx.x & 7;
    const int t  = threadIdx.x;
    const int cg = t & 63;
    const int rg = t >> 6;
    const int colA = cg * 4;
    const int row0 = rg * 8;
    const int k0 = ks * 64;

    const size_t sl = (size_t)NNEUR * BATCH * HID;

    __shared__ float xs[BATCH][64];
    #pragma unroll
    for (int q = 0; q < 2; ++q) {                 // 32*16 float4 = 512
        int fi  = t + 256 * q;
        int row = fi >> 4;
        int c4  = fi & 15;
        const float* a = p2 + ((size_t)n * BATCH + row) * HID + k0 + c4 * 4;
        float4 s0 = *((const float4*)(a));
        float4 s1 = *((const float4*)(a + sl));
        float4 s2 = *((const float4*)(a + 2 * sl));
        float4 s3 = *((const float4*)(a + 3 * sl));
        float4 s4 = *((const float4*)(a + 4 * sl));
        float4 s5 = *((const float4*)(a + 5 * sl));
        float4 s6 = *((const float4*)(a + 6 * sl));
        float4 s7 = *((const float4*)(a + 7 * sl));
        float4 bb = *((const float4*)(b2 + (size_t)n * HID + k0 + c4 * 4));
        *((float4*)&xs[row][c4 * 4]) = make_float4(
            geluf(s0.x+s1.x+s2.x+s3.x+s4.x+s5.x+s6.x+s7.x + bb.x),
            geluf(s0.y+s1.y+s2.y+s3.y+s4.y+s5.y+s6.y+s7.y + bb.y),
            geluf(s0.z+s1.z+s2.z+s3.z+s4.z+s5.z+s6.z+s7.z + bb.z),
            geluf(s0.w+s1.w+s2.w+s3.w+s4.w+s5.w+s6.w+s7.w + bb.w));
    }
    __syncthreads();

    const float* W = W3 + (size_t)n * HID * MODEL_DIM + (size_t)k0 * MODEL_DIM + colA;

    float acc[8][4];
    #pragma unroll
    for (int i = 0; i < 8; ++i)
        #pragma unroll
        for (int j = 0; j < 4; ++j) acc[i][j] = 0.0f;

    for (int kg = 0; kg < 64; kg += 4) {
        float4 xv[8];
        #pragma unroll
        for (int i = 0; i < 8; ++i)
            xv[i] = *((const float4*)&xs[row0 + i][kg]);
        #pragma unroll
        for (int j = 0; j < 4; ++j) {
            float4 wa = *((const float4*)(W + (size_t)(kg + j) * MODEL_DIM));
            #pragma unroll
            for (int i = 0; i < 8; ++i) {
                float xvv = f4c(xv[i], j);
                acc[i][0] = fmaf(xvv, wa.x, acc[i][0]);
                acc[i][1] = fmaf(xvv, wa.y, acc[i][1]);
                acc[i][2] = fmaf(xvv, wa.z, acc[i][2]);
                acc[i][3] = fmaf(xvv, wa.w, acc[i][3]);
            }
        }
    }
    float* P = p3 + (size_t)(ks * NNEUR + n) * BATCH * MODEL_DIM;
    #pragma unroll
    for (int i = 0; i < 8; ++i)
        *((float4*)(P + (size_t)(row0 + i) * MODEL_DIM + colA)) =
            make_float4(acc[i][0], acc[i][1], acc[i][2], acc[i][3]);
}

// ---------------------------------------------------------------------------
// K4: y = sum(p3[0..7]) + b3 ; LayerNorm ; oscillator mod ; f32 store
// ---------------------------------------------------------------------------
__global__ __launch_bounds__(256) void k_final(
        const float* __restrict__ p3, const float* __restrict__ b3,
        const float* __restrict__ gamma, const float* __restrict__ beta,
        const int* __restrict__ tick, float* __restrict__ out) {
    const int n  = blockIdx.x >> 3;
    const int bq = blockIdx.x & 7;
    const int t  = threadIdx.x;
    const int w  = t >> 6;
    const int lane = t & 63;
    const int b  = bq * 4 + w;

    const size_t par0 = (size_t)n * MODEL_DIM;
    const size_t rowoff = ((size_t)n * BATCH + b) * MODEL_DIM;
    const size_t sl = (size_t)NNEUR * BATCH * MODEL_DIM;

    float y[4];
    #pragma unroll
    for (int j = 0; j < 4; ++j) {
        int d = lane + 64 * j;
        float v = b3[par0 + d];
        #pragma unroll
        for (int s = 0; s < 8; ++s)
            v += p3[s * sl + rowoff + d];
        y[j] = v;
    }
    float s = y[0] + y[1] + y[2] + y[3];
    #pragma unroll
    for (int off = 32; off > 0; off >>= 1) s += __shfl_xor(s, off);
    float mu = s * (1.0f / 256.0f);
    float q = 0.0f;
    #pragma unroll
    for (int j = 0; j < 4; ++j) { float d0 = y[j] - mu; q = fmaf(d0, d0, q); }
    #pragma unroll
    for (int off = 32; off > 0; off >>= 1) q += __shfl_xor(q, off);
    float inv = rsqrtf(q * (1.0f / 256.0f) + 1e-5f);

    const double TWO_PI = 6.283185307179586476925287;
    double freq  = 0.5 * pow(80.0, (double)n * (1.0 / 63.0));
    double phase = fmod((double)n * 2.3571, TWO_PI);
    double tt    = (double)(*tick) * 0.1;
    float mod = (float)(1.0 + 0.5 * sin(TWO_PI * freq * tt + phase));

    #pragma unroll
    for (int j = 0; j < 4; ++j) {
        int d = lane + 64 * j;
        float o = (y[j] - mu) * inv * gamma[par0 + d] + beta[par0 + d];
        o *= mod;
        out[((size_t)b * NNEUR + n) * MODEL_DIM + d] = o;
    }
}

// ---------------------------------------------------------------------------
extern "C" void kernel_launch(void* const* d_in, const int* in_sizes, int n_in,
                              void* d_out, int out_size, void* d_ws, size_t ws_size,
                              hipStream_t stream) {
    const float* emb  = (const float*)d_in[0];
    const float* pre  = (const float*)d_in[1];
    const float* Wp   = (const float*)d_in[2];
    const float* bp   = (const float*)d_in[3];
    const float* W1   = (const float*)d_in[4];
    const float* b1   = (const float*)d_in[5];
    const float* W2   = (const float*)d_in[6];
    const float* b2   = (const float*)d_in[7];
    const float* W3   = (const float*)d_in[8];
    const float* b3   = (const float*)d_in[9];
    const float* gam  = (const float*)d_in[10];
    const float* bet  = (const float*)d_in[11];
    const int* tick   = (const int*)d_in[12];

    float* ws = (float*)d_ws;
    float* x  = ws;                      // 32*2304          =   73728 f32
    float* p1 = x  + 73728;              // [8][64][32][512] = 8388608 f32
    float* p2 = p1 + 8388608;            // [8][64][32][512] = 8388608 f32
    float* p3 = p1;                      // [8][64][32][256] = 4194304 f32 (aliases dead p1)
    float* out = (float*)d_out;

    k_build_x<<<32,  256, 0, stream>>>(emb, pre, Wp, bp, x);
    k_layer1 <<<512, 256, 0, stream>>>(x, W1, p1);
    k_layer2 <<<512, 256, 0, stream>>>(p1, b1, W2, p2);
    k_layer3 <<<512, 256, 0, stream>>>(p2, b2, W3, p3);
    k_final  <<<512, 256, 0, stream>>>(p3, b3, gam, bet, tick, out);
}

// Round 8
// 182.091 us; speedup vs baseline: 1.2178x; 1.1807x over previous
//
#include <hip/hip_runtime.h>
#include <hip/hip_bf16.h>

#define MODEL_DIM 256
#define HIST 8
#define HID 512
#define NNEUR 64
#define IN_DIM 2304   // MODEL_DIM * (1 + HIST)
#define BATCH 32

__device__ __forceinline__ float geluf(float x) {
    return 0.5f * x * (1.0f + erff(x * 0.70710678118654752440f));
}
__device__ __forceinline__ float f4c(const float4& v, int j) {
    switch (j) { case 0: return v.x; case 1: return v.y; case 2: return v.z; default: return v.w; }
}

// ---------------------------------------------------------------------------
// K0: x[b][0:256] = emb[b] @ Wp + bp ; x[b][256:2304] = pre_activations flat
// ---------------------------------------------------------------------------
__global__ __launch_bounds__(256) void k_build_x(
        const float* __restrict__ emb, const float* __restrict__ pre,
        const float* __restrict__ Wp, const float* __restrict__ bp,
        float* __restrict__ x) {
    const int b = blockIdx.x;
    const int d = threadIdx.x;

    __shared__ float e[MODEL_DIM];
    e[d] = emb[b * MODEL_DIM + d];
    __syncthreads();

    float acc = bp[d];
    #pragma unroll 4
    for (int k = 0; k < MODEL_DIM; ++k)
        acc = fmaf(e[k], Wp[(size_t)k * MODEL_DIM + d], acc);
    x[b * IN_DIM + d] = acc;

    #pragma unroll
    for (int r = 0; r < HIST; ++r)
        x[b * IN_DIM + MODEL_DIM + r * MODEL_DIM + d] = pre[r * MODEL_DIM + d];
}

// ---------------------------------------------------------------------------
// K1: layer1. grid 1024 = n(64) x ct(2: 256-col half) x ks(8: K=288).
// block 256 = cg(64 lanes -> 4 cols, 1KB coalesced/wave) x rg(4 -> 8 rows).
// 16 waves/CU, ~90 VGPR (no spill). p1[8][64][32][512] f32
// ---------------------------------------------------------------------------
__global__ __launch_bounds__(256, 4) void k_layer1(
        const float* __restrict__ x, const float* __restrict__ W1,
        float* __restrict__ p1) {
    const int bid = blockIdx.x;
    const int n  = bid >> 4;
    const int ct = (bid >> 3) & 1;
    const int ks = bid & 7;
    const int t  = threadIdx.x;
    const int cg = t & 63;
    const int rg = t >> 6;
    const int col0 = ct * 256 + cg * 4;
    const int row0 = rg * 8;
    const int k0 = ks * 288;

    __shared__ float xs[BATCH][288];
    #pragma unroll
    for (int q = 0; q < 9; ++q) {                 // 32*72 float4 = 2304
        int fi  = t + 256 * q;
        int row = fi / 72;
        int c4  = fi - row * 72;
        *((float4*)&xs[row][c4 * 4]) =
            *((const float4*)(x + (size_t)row * IN_DIM + k0 + c4 * 4));
    }
    __syncthreads();

    const float* W = W1 + (size_t)n * IN_DIM * HID + (size_t)k0 * HID + col0;

    float acc[8][4];
    #pragma unroll
    for (int i = 0; i < 8; ++i)
        #pragma unroll
        for (int j = 0; j < 4; ++j) acc[i][j] = 0.0f;

    for (int kg = 0; kg < 288; kg += 4) {
        float4 xv[8];
        #pragma unroll
        for (int i = 0; i < 8; ++i)
            xv[i] = *((const float4*)&xs[row0 + i][kg]);
        #pragma unroll
        for (int j = 0; j < 4; ++j) {
            float4 w = *((const float4*)(W + (size_t)(kg + j) * HID));
            #pragma unroll
            for (int i = 0; i < 8; ++i) {
                float xvv = f4c(xv[i], j);
                acc[i][0] = fmaf(xvv, w.x, acc[i][0]);
                acc[i][1] = fmaf(xvv, w.y, acc[i][1]);
                acc[i][2] = fmaf(xvv, w.z, acc[i][2]);
                acc[i][3] = fmaf(xvv, w.w, acc[i][3]);
            }
        }
    }
    float* P = p1 + (size_t)(ks * NNEUR + n) * BATCH * HID;
    #pragma unroll
    for (int i = 0; i < 8; ++i)
        *((float4*)(P + (size_t)(row0 + i) * HID + col0)) =
            make_float4(acc[i][0], acc[i][1], acc[i][2], acc[i][3]);
}

// ---------------------------------------------------------------------------
// K2: layer2. h1 = gelu(sum p1[0..7] + b1) staged. grid 1024 = n(64) x
// ct(2) x ks(8: K=64). block 256: cg(64->4 cols) x rg(4->8 rows).
// p2[8][64][32][512] f32
// ---------------------------------------------------------------------------
__global__ __launch_bounds__(256, 4) void k_layer2(
        const float* __restrict__ p1, const float* __restrict__ b1,
        const float* __restrict__ W2, float* __restrict__ p2) {
    const int bid = blockIdx.x;
    const int n  = bid >> 4;
    const int ct = (bid >> 3) & 1;
    const int ks = bid & 7;
    const int t  = threadIdx.x;
    const int cg = t & 63;
    const int rg = t >> 6;
    const int col0 = ct * 256 + cg * 4;
    const int row0 = rg * 8;
    const int k0 = ks * 64;

    const size_t sl = (size_t)NNEUR * BATCH * HID;

    __shared__ float xs[BATCH][64];
    #pragma unroll
    for (int q = 0; q < 2; ++q) {                 // 32*16 float4 = 512
        int fi  = t + 256 * q;
        int row = fi >> 4;
        int c4  = fi & 15;
        const float* a = p1 + ((size_t)n * BATCH + row) * HID + k0 + c4 * 4;
        float4 s0 = *((const float4*)(a));
        float4 s1 = *((const float4*)(a + sl));
        float4 s2 = *((const float4*)(a + 2 * sl));
        float4 s3 = *((const float4*)(a + 3 * sl));
        float4 s4 = *((const float4*)(a + 4 * sl));
        float4 s5 = *((const float4*)(a + 5 * sl));
        float4 s6 = *((const float4*)(a + 6 * sl));
        float4 s7 = *((const float4*)(a + 7 * sl));
        float4 bb = *((const float4*)(b1 + (size_t)n * HID + k0 + c4 * 4));
        *((float4*)&xs[row][c4 * 4]) = make_float4(
            geluf(s0.x+s1.x+s2.x+s3.x+s4.x+s5.x+s6.x+s7.x + bb.x),
            geluf(s0.y+s1.y+s2.y+s3.y+s4.y+s5.y+s6.y+s7.y + bb.y),
            geluf(s0.z+s1.z+s2.z+s3.z+s4.z+s5.z+s6.z+s7.z + bb.z),
            geluf(s0.w+s1.w+s2.w+s3.w+s4.w+s5.w+s6.w+s7.w + bb.w));
    }
    __syncthreads();

    const float* W = W2 + (size_t)n * HID * HID + (size_t)k0 * HID + col0;

    float acc[8][4];
    #pragma unroll
    for (int i = 0; i < 8; ++i)
        #pragma unroll
        for (int j = 0; j < 4; ++j) acc[i][j] = 0.0f;

    for (int kg = 0; kg < 64; kg += 4) {
        float4 xv[8];
        #pragma unroll
        for (int i = 0; i < 8; ++i)
            xv[i] = *((const float4*)&xs[row0 + i][kg]);
        #pragma unroll
        for (int j = 0; j < 4; ++j) {
            float4 w = *((const float4*)(W + (size_t)(kg + j) * HID));
            #pragma unroll
            for (int i = 0; i < 8; ++i) {
                float xvv = f4c(xv[i], j);
                acc[i][0] = fmaf(xvv, w.x, acc[i][0]);
                acc[i][1] = fmaf(xvv, w.y, acc[i][1]);
                acc[i][2] = fmaf(xvv, w.z, acc[i][2]);
                acc[i][3] = fmaf(xvv, w.w, acc[i][3]);
            }
        }
    }
    float* P = p2 + (size_t)(ks * NNEUR + n) * BATCH * HID;
    #pragma unroll
    for (int i = 0; i < 8; ++i)
        *((float4*)(P + (size_t)(row0 + i) * HID + col0)) =
            make_float4(acc[i][0], acc[i][1], acc[i][2], acc[i][3]);
}

// ---------------------------------------------------------------------------
// K3: layer3. h2 = gelu(sum p2[0..7] + b2) staged. grid 1024 = n(64) x
// ks(16: K=32). block 256: cg(64 -> 4 cols, all 256) x rg(4 -> 8 rows).
// p3[16][64][32][256] f32
// ---------------------------------------------------------------------------
__global__ __launch_bounds__(256, 4) void k_layer3(
        const float* __restrict__ p2, const float* __restrict__ b2,
        const float* __restrict__ W3, float* __restrict__ p3) {
    const int bid = blockIdx.x;
    const int n  = bid >> 4;
    const int ks = bid & 15;
    const int t  = threadIdx.x;
    const int cg = t & 63;
    const int rg = t >> 6;
    const int col0 = cg * 4;
    const int row0 = rg * 8;
    const int k0 = ks * 32;

    const size_t sl = (size_t)NNEUR * BATCH * HID;

    __shared__ float xs[BATCH][32];
    {                                             // 32*8 float4 = 256
        int row = t >> 3;
        int c4  = t & 7;
        const float* a = p2 + ((size_t)n * BATCH + row) * HID + k0 + c4 * 4;
        float4 s0 = *((const float4*)(a));
        float4 s1 = *((const float4*)(a + sl));
        float4 s2 = *((const float4*)(a + 2 * sl));
        float4 s3 = *((const float4*)(a + 3 * sl));
        float4 s4 = *((const float4*)(a + 4 * sl));
        float4 s5 = *((const float4*)(a + 5 * sl));
        float4 s6 = *((const float4*)(a + 6 * sl));
        float4 s7 = *((const float4*)(a + 7 * sl));
        float4 bb = *((const float4*)(b2 + (size_t)n * HID + k0 + c4 * 4));
        *((float4*)&xs[row][c4 * 4]) = make_float4(
            geluf(s0.x+s1.x+s2.x+s3.x+s4.x+s5.x+s6.x+s7.x + bb.x),
            geluf(s0.y+s1.y+s2.y+s3.y+s4.y+s5.y+s6.y+s7.y + bb.y),
            geluf(s0.z+s1.z+s2.z+s3.z+s4.z+s5.z+s6.z+s7.z + bb.z),
            geluf(s0.w+s1.w+s2.w+s3.w+s4.w+s5.w+s6.w+s7.w + bb.w));
    }
    __syncthreads();

    const float* W = W3 + (size_t)n * HID * MODEL_DIM + (size_t)k0 * MODEL_DIM + col0;

    float acc[8][4];
    #pragma unroll
    for (int i = 0; i < 8; ++i)
        #pragma unroll
        for (int j = 0; j < 4; ++j) acc[i][j] = 0.0f;

    for (int kg = 0; kg < 32; kg += 4) {
        float4 xv[8];
        #pragma unroll
        for (int i = 0; i < 8; ++i)
            xv[i] = *((const float4*)&xs[row0 + i][kg]);
        #pragma unroll
        for (int j = 0; j < 4; ++j) {
            float4 w = *((const float4*)(W + (size_t)(kg + j) * MODEL_DIM));
            #pragma unroll
            for (int i = 0; i < 8; ++i) {
                float xvv = f4c(xv[i], j);
                acc[i][0] = fmaf(xvv, w.x, acc[i][0]);
                acc[i][1] = fmaf(xvv, w.y, acc[i][1]);
                acc[i][2] = fmaf(xvv, w.z, acc[i][2]);
                acc[i][3] = fmaf(xvv, w.w, acc[i][3]);
            }
        }
    }
    float* P = p3 + (size_t)(ks * NNEUR + n) * BATCH * MODEL_DIM;
    #pragma unroll
    for (int i = 0; i < 8; ++i)
        *((float4*)(P + (size_t)(row0 + i) * MODEL_DIM + col0)) =
            make_float4(acc[i][0], acc[i][1], acc[i][2], acc[i][3]);
}

// ---------------------------------------------------------------------------
// K4: y = sum(p3[0..15]) + b3 ; LayerNorm ; oscillator mod ; f32 store
// grid 512 = n(64) x bquad(8); block 256 = 4 waves, wave w -> batch row
// ---------------------------------------------------------------------------
__global__ __launch_bounds__(256) void k_final(
        const float* __restrict__ p3, const float* __restrict__ b3,
        const float* __restrict__ gamma, const float* __restrict__ beta,
        const int* __restrict__ tick, float* __restrict__ out) {
    const int n  = blockIdx.x >> 3;
    const int bq = blockIdx.x & 7;
    const int t  = threadIdx.x;
    const int w  = t >> 6;
    const int lane = t & 63;
    const int b  = bq * 4 + w;

    const size_t par0 = (size_t)n * MODEL_DIM;
    const size_t rowoff = ((size_t)n * BATCH + b) * MODEL_DIM;
    const size_t sl = (size_t)NNEUR * BATCH * MODEL_DIM;

    float y[4];
    #pragma unroll
    for (int j = 0; j < 4; ++j) {
        int d = lane + 64 * j;
        float v = b3[par0 + d];
        #pragma unroll
        for (int s = 0; s < 16; ++s)
            v += p3[s * sl + rowoff + d];
        y[j] = v;
    }
    float s = y[0] + y[1] + y[2] + y[3];
    #pragma unroll
    for (int off = 32; off > 0; off >>= 1) s += __shfl_xor(s, off);
    float mu = s * (1.0f / 256.0f);
    float q = 0.0f;
    #pragma unroll
    for (int j = 0; j < 4; ++j) { float d0 = y[j] - mu; q = fmaf(d0, d0, q); }
    #pragma unroll
    for (int off = 32; off > 0; off >>= 1) q += __shfl_xor(q, off);
    float inv = rsqrtf(q * (1.0f / 256.0f) + 1e-5f);

    const double TWO_PI = 6.283185307179586476925287;
    double freq  = 0.5 * pow(80.0, (double)n * (1.0 / 63.0));
    double phase = fmod((double)n * 2.3571, TWO_PI);
    double tt    = (double)(*tick) * 0.1;
    float mod = (float)(1.0 + 0.5 * sin(TWO_PI * freq * tt + phase));

    #pragma unroll
    for (int j = 0; j < 4; ++j) {
        int d = lane + 64 * j;
        float o = (y[j] - mu) * inv * gamma[par0 + d] + beta[par0 + d];
        o *= mod;
        out[((size_t)b * NNEUR + n) * MODEL_DIM + d] = o;
    }
}

// ---------------------------------------------------------------------------
extern "C" void kernel_launch(void* const* d_in, const int* in_sizes, int n_in,
                              void* d_out, int out_size, void* d_ws, size_t ws_size,
                              hipStream_t stream) {
    const float* emb  = (const float*)d_in[0];
    const float* pre  = (const float*)d_in[1];
    const float* Wp   = (const float*)d_in[2];
    const float* bp   = (const float*)d_in[3];
    const float* W1   = (const float*)d_in[4];
    const float* b1   = (const float*)d_in[5];
    const float* W2   = (const float*)d_in[6];
    const float* b2   = (const float*)d_in[7];
    const float* W3   = (const float*)d_in[8];
    const float* b3   = (const float*)d_in[9];
    const float* gam  = (const float*)d_in[10];
    const float* bet  = (const float*)d_in[11];
    const int* tick   = (const int*)d_in[12];

    float* ws = (float*)d_ws;
    float* x  = ws;                      // 32*2304           =   73728 f32
    float* p1 = x  + 73728;              // [8][64][32][512]  = 8388608 f32
    float* p2 = p1 + 8388608;            // [8][64][32][512]  = 8388608 f32
    float* p3 = p2 + 8388608;            // [16][64][32][256] = 8388608 f32
    float* out = (float*)d_out;

    k_build_x<<<32,   256, 0, stream>>>(emb, pre, Wp, bp, x);
    k_layer1 <<<1024, 256, 0, stream>>>(x, W1, p1);
    k_layer2 <<<1024, 256, 0, stream>>>(p1, b1, W2, p2);
    k_layer3 <<<1024, 256, 0, stream>>>(p2, b2, W3, p3);
    k_final  <<<512,  256, 0, stream>>>(p3, b3, gam, bet, tick, out);
}

// Round 9
// 165.193 us; speedup vs baseline: 1.3423x; 1.1023x over previous
//
#include <hip/hip_runtime.h>
#include <hip/hip_bf16.h>

#define MODEL_DIM 256
#define HIST 8
#define HID 512
#define NNEUR 64
#define IN_DIM 2304   // MODEL_DIM * (1 + HIST)
#define BATCH 32

__device__ __forceinline__ float geluf(float x) {
    return 0.5f * x * (1.0f + erff(x * 0.70710678118654752440f));
}
__device__ __forceinline__ float f4c(const float4& v, int j) {
    switch (j) { case 0: return v.x; case 1: return v.y; case 2: return v.z; default: return v.w; }
}

// ---------------------------------------------------------------------------
// K0: proj[b][d] = emb[b] @ Wp + bp   (32 x 256). History is NOT materialized
// (it is batch-broadcast; handled algebraically in layer 1).
// ---------------------------------------------------------------------------
__global__ __launch_bounds__(256) void k_build_x(
        const float* __restrict__ emb, const float* __restrict__ pre,
        const float* __restrict__ Wp, const float* __restrict__ bp,
        float* __restrict__ proj) {
    const int b = blockIdx.x;
    const int d = threadIdx.x;

    __shared__ float e[MODEL_DIM];
    e[d] = emb[b * MODEL_DIM + d];
    __syncthreads();

    float acc = bp[d];
    #pragma unroll 4
    for (int k = 0; k < MODEL_DIM; ++k)
        acc = fmaf(e[k], Wp[(size_t)k * MODEL_DIM + d], acc);
    proj[b * MODEL_DIM + d] = acc;
}

// ---------------------------------------------------------------------------
// K1 fused: two block types in one grid (1024 blocks total).
//  bid <  512 : HIST blocks.  n = bid>>3, ks = bid&7 (K=256 history rows).
//    ph[ks][n][c] = sum_k pre[ks*256+k] * W1[n][256+ks*256+k][c]
//    Pure stream: 1 FMA per W element (history is batch-broadcast).
//  bid >= 512 : PROJ blocks. r8-style tile over W1 rows 0..255 with proj.
//    pp[ks][n][b][c], ks=4 (K=64 each), ct = 256-col half.
// ---------------------------------------------------------------------------
__global__ __launch_bounds__(256, 4) void k_layer1(
        const float* __restrict__ pre, const float* __restrict__ proj,
        const float* __restrict__ W1,
        float* __restrict__ ph, float* __restrict__ pp) {
    __shared__ float lds[2048];
    const int bid = blockIdx.x;
    const int t = threadIdx.x;

    if (bid < 512) {
        // ---------------- history stream blocks ----------------
        const int n  = bid >> 3;
        const int ks = bid & 7;
        const int c4 = t & 127;            // float4 col group: cols c4*4..+3
        const int kh = t >> 7;             // k half (128 each)
        const int k0 = ks * 256;

        float* ps = lds;                   // 256 floats of pre
        ps[t] = pre[k0 + t];
        __syncthreads();

        const float* W = W1 + (size_t)n * IN_DIM * HID
                            + (size_t)(MODEL_DIM + k0 + kh * 128) * HID + c4 * 4;
        float4 a = make_float4(0.f, 0.f, 0.f, 0.f);
        const float* psk = ps + kh * 128;
        #pragma unroll 8
        for (int kk = 0; kk < 128; ++kk) {
            float4 w = *((const float4*)(W + (size_t)kk * HID));
            float s = psk[kk];
            a.x = fmaf(s, w.x, a.x);
            a.y = fmaf(s, w.y, a.y);
            a.z = fmaf(s, w.z, a.z);
            a.w = fmaf(s, w.w, a.w);
        }
        // combine the two k-halves via LDS
        float4* red = (float4*)(lds + 256);     // 128 float4
        if (kh == 1) red[c4] = a;
        __syncthreads();
        if (kh == 0) {
            float4 b4 = red[c4];
            a.x += b4.x; a.y += b4.y; a.z += b4.z; a.w += b4.w;
            *((float4*)(ph + ((size_t)ks * NNEUR + n) * HID + c4 * 4)) = a;
        }
    } else {
        // ---------------- proj GEMM blocks ----------------
        const int pb = bid - 512;
        const int n  = pb >> 3;
        const int ct = (pb >> 2) & 1;
        const int ks = pb & 3;             // K = 64 of the 256 proj rows
        const int cg = t & 63;
        const int rg = t >> 6;
        const int col0 = ct * 256 + cg * 4;
        const int row0 = rg * 8;
        const int k0 = ks * 64;

        float (*xs)[64] = (float(*)[64])lds;     // 32 x 64 slice of proj
        #pragma unroll
        for (int q = 0; q < 2; ++q) {            // 32*16 float4 = 512
            int fi  = t + 256 * q;
            int row = fi >> 4;
            int c4  = fi & 15;
            *((float4*)&xs[row][c4 * 4]) =
                *((const float4*)(proj + (size_t)row * MODEL_DIM + k0 + c4 * 4));
        }
        __syncthreads();

        const float* W = W1 + (size_t)n * IN_DIM * HID + (size_t)k0 * HID + col0;

        float acc[8][4];
        #pragma unroll
        for (int i = 0; i < 8; ++i)
            #pragma unroll
            for (int j = 0; j < 4; ++j) acc[i][j] = 0.0f;

        for (int kg = 0; kg < 64; kg += 4) {
            float4 xv[8];
            #pragma unroll
            for (int i = 0; i < 8; ++i)
                xv[i] = *((const float4*)&xs[row0 + i][kg]);
            #pragma unroll
            for (int j = 0; j < 4; ++j) {
                float4 w = *((const float4*)(W + (size_t)(kg + j) * HID));
                #pragma unroll
                for (int i = 0; i < 8; ++i) {
                    float xvv = f4c(xv[i], j);
                    acc[i][0] = fmaf(xvv, w.x, acc[i][0]);
                    acc[i][1] = fmaf(xvv, w.y, acc[i][1]);
                    acc[i][2] = fmaf(xvv, w.z, acc[i][2]);
                    acc[i][3] = fmaf(xvv, w.w, acc[i][3]);
                }
            }
        }
        float* P = pp + (size_t)(ks * NNEUR + n) * BATCH * HID;
        #pragma unroll
        for (int i = 0; i < 8; ++i)
            *((float4*)(P + (size_t)(row0 + i) * HID + col0)) =
                make_float4(acc[i][0], acc[i][1], acc[i][2], acc[i][3]);
    }
}

// ---------------------------------------------------------------------------
// K2: layer2. h1 = gelu(sum_{s<4} pp[s] + sum_{s<8} ph[s] + b1) staged.
// grid 1024 = n(64) x ct(2) x ks(8: K=64). block 256: cg(64->4 cols) x
// rg(4->8 rows). p2[8][64][32][512] f32
// ---------------------------------------------------------------------------
__global__ __launch_bounds__(256, 4) void k_layer2(
        const float* __restrict__ pp, const float* __restrict__ ph,
        const float* __restrict__ b1,
        const float* __restrict__ W2, float* __restrict__ p2) {
    const int bid = blockIdx.x;
    const int n  = bid >> 4;
    const int ct = (bid >> 3) & 1;
    const int ks = bid & 7;
    const int t  = threadIdx.x;
    const int cg = t & 63;
    const int rg = t >> 6;
    const int col0 = ct * 256 + cg * 4;
    const int row0 = rg * 8;
    const int k0 = ks * 64;

    const size_t slp = (size_t)NNEUR * BATCH * HID;   // pp slice stride
    const size_t slh = (size_t)NNEUR * HID;           // ph slice stride

    __shared__ float xs[BATCH][64];
    #pragma unroll
    for (int q = 0; q < 2; ++q) {                 // 32*16 float4 = 512
        int fi  = t + 256 * q;
        int row = fi >> 4;
        int c4  = fi & 15;
        const float* a = pp + ((size_t)n * BATCH + row) * HID + k0 + c4 * 4;
        float4 s0 = *((const float4*)(a));
        float4 s1 = *((const float4*)(a + slp));
        float4 s2 = *((const float4*)(a + 2 * slp));
        float4 s3 = *((const float4*)(a + 3 * slp));
        const float* h = ph + (size_t)n * HID + k0 + c4 * 4;
        float4 h0 = *((const float4*)(h));
        float4 h1 = *((const float4*)(h + slh));
        float4 h2 = *((const float4*)(h + 2 * slh));
        float4 h3 = *((const float4*)(h + 3 * slh));
        float4 h4 = *((const float4*)(h + 4 * slh));
        float4 h5 = *((const float4*)(h + 5 * slh));
        float4 h6 = *((const float4*)(h + 6 * slh));
        float4 h7 = *((const float4*)(h + 7 * slh));
        float4 bb = *((const float4*)(b1 + (size_t)n * HID + k0 + c4 * 4));
        *((float4*)&xs[row][c4 * 4]) = make_float4(
            geluf(s0.x+s1.x+s2.x+s3.x + h0.x+h1.x+h2.x+h3.x+h4.x+h5.x+h6.x+h7.x + bb.x),
            geluf(s0.y+s1.y+s2.y+s3.y + h0.y+h1.y+h2.y+h3.y+h4.y+h5.y+h6.y+h7.y + bb.y),
            geluf(s0.z+s1.z+s2.z+s3.z + h0.z+h1.z+h2.z+h3.z+h4.z+h5.z+h6.z+h7.z + bb.z),
            geluf(s0.w+s1.w+s2.w+s3.w + h0.w+h1.w+h2.w+h3.w+h4.w+h5.w+h6.w+h7.w + bb.w));
    }
    __syncthreads();

    const float* W = W2 + (size_t)n * HID * HID + (size_t)k0 * HID + col0;

    float acc[8][4];
    #pragma unroll
    for (int i = 0; i < 8; ++i)
        #pragma unroll
        for (int j = 0; j < 4; ++j) acc[i][j] = 0.0f;

    for (int kg = 0; kg < 64; kg += 4) {
        float4 xv[8];
        #pragma unroll
        for (int i = 0; i < 8; ++i)
            xv[i] = *((const float4*)&xs[row0 + i][kg]);
        #pragma unroll
        for (int j = 0; j < 4; ++j) {
            float4 w = *((const float4*)(W + (size_t)(kg + j) * HID));
            #pragma unroll
            for (int i = 0; i < 8; ++i) {
                float xvv = f4c(xv[i], j);
                acc[i][0] = fmaf(xvv, w.x, acc[i][0]);
                acc[i][1] = fmaf(xvv, w.y, acc[i][1]);
                acc[i][2] = fmaf(xvv, w.z, acc[i][2]);
                acc[i][3] = fmaf(xvv, w.w, acc[i][3]);
            }
        }
    }
    float* P = p2 + (size_t)(ks * NNEUR + n) * BATCH * HID;
    #pragma unroll
    for (int i = 0; i < 8; ++i)
        *((float4*)(P + (size_t)(row0 + i) * HID + col0)) =
            make_float4(acc[i][0], acc[i][1], acc[i][2], acc[i][3]);
}

// ---------------------------------------------------------------------------
// K3: layer3. h2 = gelu(sum p2[0..7] + b2) staged. grid 1024 = n(64) x
// ks(16: K=32). block 256: cg(64 -> 4 cols, all 256) x rg(4 -> 8 rows).
// p3[16][64][32][256] f32
// ---------------------------------------------------------------------------
__global__ __launch_bounds__(256, 4) void k_layer3(
        const float* __restrict__ p2, const float* __restrict__ b2,
        const float* __restrict__ W3, float* __restrict__ p3) {
    const int bid = blockIdx.x;
    const int n  = bid >> 4;
    const int ks = bid & 15;
    const int t  = threadIdx.x;
    const int cg = t & 63;
    const int rg = t >> 6;
    const int col0 = cg * 4;
    const int row0 = rg * 8;
    const int k0 = ks * 32;

    const size_t sl = (size_t)NNEUR * BATCH * HID;

    __shared__ float xs[BATCH][32];
    {                                             // 32*8 float4 = 256
        int row = t >> 3;
        int c4  = t & 7;
        const float* a = p2 + ((size_t)n * BATCH + row) * HID + k0 + c4 * 4;
        float4 s0 = *((const float4*)(a));
        float4 s1 = *((const float4*)(a + sl));
        float4 s2 = *((const float4*)(a + 2 * sl));
        float4 s3 = *((const float4*)(a + 3 * sl));
        float4 s4 = *((const float4*)(a + 4 * sl));
        float4 s5 = *((const float4*)(a + 5 * sl));
        float4 s6 = *((const float4*)(a + 6 * sl));
        float4 s7 = *((const float4*)(a + 7 * sl));
        float4 bb = *((const float4*)(b2 + (size_t)n * HID + k0 + c4 * 4));
        *((float4*)&xs[row][c4 * 4]) = make_float4(
            geluf(s0.x+s1.x+s2.x+s3.x+s4.x+s5.x+s6.x+s7.x + bb.x),
            geluf(s0.y+s1.y+s2.y+s3.y+s4.y+s5.y+s6.y+s7.y + bb.y),
            geluf(s0.z+s1.z+s2.z+s3.z+s4.z+s5.z+s6.z+s7.z + bb.z),
            geluf(s0.w+s1.w+s2.w+s3.w+s4.w+s5.w+s6.w+s7.w + bb.w));
    }
    __syncthreads();

    const float* W = W3 + (size_t)n * HID * MODEL_DIM + (size_t)k0 * MODEL_DIM + col0;

    float acc[8][4];
    #pragma unroll
    for (int i = 0; i < 8; ++i)
        #pragma unroll
        for (int j = 0; j < 4; ++j) acc[i][j] = 0.0f;

    for (int kg = 0; kg < 32; kg += 4) {
        float4 xv[8];
        #pragma unroll
        for (int i = 0; i < 8; ++i)
            xv[i] = *((const float4*)&xs[row0 + i][kg]);
        #pragma unroll
        for (int j = 0; j < 4; ++j) {
            float4 w = *((const float4*)(W + (size_t)(kg + j) * MODEL_DIM));
            #pragma unroll
            for (int i = 0; i < 8; ++i) {
                float xvv = f4c(xv[i], j);
                acc[i][0] = fmaf(xvv, w.x, acc[i][0]);
                acc[i][1] = fmaf(xvv, w.y, acc[i][1]);
                acc[i][2] = fmaf(xvv, w.z, acc[i][2]);
                acc[i][3] = fmaf(xvv, w.w, acc[i][3]);
            }
        }
    }
    float* P = p3 + (size_t)(ks * NNEUR + n) * BATCH * MODEL_DIM;
    #pragma unroll
    for (int i = 0; i < 8; ++i)
        *((float4*)(P + (size_t)(row0 + i) * MODEL_DIM + col0)) =
            make_float4(acc[i][0], acc[i][1], acc[i][2], acc[i][3]);
}

// ---------------------------------------------------------------------------
// K4: y = sum(p3[0..15]) + b3 ; LayerNorm ; oscillator mod ; f32 store
// ---------------------------------------------------------------------------
__global__ __launch_bounds__(256) void k_final(
        const float* __restrict__ p3, const float* __restrict__ b3,
        const float* __restrict__ gamma, const float* __restrict__ beta,
        const int* __restrict__ tick, float* __restrict__ out) {
    const int n  = blockIdx.x >> 3;
    const int bq = blockIdx.x & 7;
    const int t  = threadIdx.x;
    const int w  = t >> 6;
    const int lane = t & 63;
    const int b  = bq * 4 + w;

    const size_t par0 = (size_t)n * MODEL_DIM;
    const size_t rowoff = ((size_t)n * BATCH + b) * MODEL_DIM;
    const size_t sl = (size_t)NNEUR * BATCH * MODEL_DIM;

    float y[4];
    #pragma unroll
    for (int j = 0; j < 4; ++j) {
        int d = lane + 64 * j;
        float v = b3[par0 + d];
        #pragma unroll
        for (int s = 0; s < 16; ++s)
            v += p3[s * sl + rowoff + d];
        y[j] = v;
    }
    float s = y[0] + y[1] + y[2] + y[3];
    #pragma unroll
    for (int off = 32; off > 0; off >>= 1) s += __shfl_xor(s, off);
    float mu = s * (1.0f / 256.0f);
    float q = 0.0f;
    #pragma unroll
    for (int j = 0; j < 4; ++j) { float d0 = y[j] - mu; q = fmaf(d0, d0, q); }
    #pragma unroll
    for (int off = 32; off > 0; off >>= 1) q += __shfl_xor(q, off);
    float inv = rsqrtf(q * (1.0f / 256.0f) + 1e-5f);

    const double TWO_PI = 6.283185307179586476925287;
    double freq  = 0.5 * pow(80.0, (double)n * (1.0 / 63.0));
    double phase = fmod((double)n * 2.3571, TWO_PI);
    double tt    = (double)(*tick) * 0.1;
    float mod = (float)(1.0 + 0.5 * sin(TWO_PI * freq * tt + phase));

    #pragma unroll
    for (int j = 0; j < 4; ++j) {
        int d = lane + 64 * j;
        float o = (y[j] - mu) * inv * gamma[par0 + d] + beta[par0 + d];
        o *= mod;
        out[((size_t)b * NNEUR + n) * MODEL_DIM + d] = o;
    }
}

// ---------------------------------------------------------------------------
extern "C" void kernel_launch(void* const* d_in, const int* in_sizes, int n_in,
                              void* d_out, int out_size, void* d_ws, size_t ws_size,
                              hipStream_t stream) {
    const float* emb  = (const float*)d_in[0];
    const float* pre  = (const float*)d_in[1];
    const float* Wp   = (const float*)d_in[2];
    const float* bp   = (const float*)d_in[3];
    const float* W1   = (const float*)d_in[4];
    const float* b1   = (const float*)d_in[5];
    const float* W2   = (const float*)d_in[6];
    const float* b2   = (const float*)d_in[7];
    const float* W3   = (const float*)d_in[8];
    const float* b3   = (const float*)d_in[9];
    const float* gam  = (const float*)d_in[10];
    const float* bet  = (const float*)d_in[11];
    const int* tick   = (const int*)d_in[12];

    float* ws = (float*)d_ws;
    float* proj = ws;                    // 32*256            =    8192 f32
    float* ph = proj + 8192;             // [8][64][512]      =  262144 f32
    float* pp = ph + 262144;             // [4][64][32][512]  = 4194304 f32
    float* p2 = pp + 4194304;            // [8][64][32][512]  = 8388608 f32
    float* p3 = p2 + 8388608;            // [16][64][32][256] = 8388608 f32
    float* out = (float*)d_out;

    k_build_x<<<32,   256, 0, stream>>>(emb, pre, Wp, bp, proj);
    k_layer1 <<<1024, 256, 0, stream>>>(pre, proj, W1, ph, pp);
    k_layer2 <<<1024, 256, 0, stream>>>(pp, ph, b1, W2, p2);
    k_layer3 <<<1024, 256, 0, stream>>>(p2, b2, W3, p3);
    k_final  <<<512,  256, 0, stream>>>(p3, b3, gam, bet, tick, out);
}